// Round 1
// baseline (294.040 us; speedup 1.0000x reference)
//
#include <hip/hip_runtime.h>
#include <hip/hip_bf16.h>
#include <stdint.h>

#define BATCH  8192
#define DIN    2048
#define DOUT   2048
#define NB     256
#define KSEL   26   // ceil(0.1*256)

typedef __attribute__((ext_vector_type(4))) float f32x4;
typedef __attribute__((ext_vector_type(8))) __bf16 bf16x8;
typedef __attribute__((ext_vector_type(8))) unsigned short u16x8;
typedef __attribute__((ext_vector_type(4))) unsigned short u16x4;

__device__ __forceinline__ float bf2f(unsigned short u){
  union { unsigned int i; float f; } v; v.i = ((unsigned int)u) << 16; return v.f;
}
__device__ __forceinline__ unsigned short f2bf(float f){
  union { float f; unsigned int i; } v; v.f = f;
  unsigned int x = v.i;
  return (unsigned short)((x + 0x7FFFu + ((x >> 16) & 1u)) >> 16);  // RNE
}

// ---------------- K0a: x (f32) -> bf16 ----------------
__global__ void conv_x(const float* __restrict__ x, unsigned short* __restrict__ xb, int n4)
{
  const int stride = gridDim.x * blockDim.x;
  for (int i = blockIdx.x * blockDim.x + threadIdx.x; i < n4; i += stride){
    f32x4 v = ((const f32x4*)x)[i];
    u16x4 o;
    #pragma unroll
    for (int j = 0; j < 4; j++) o[j] = f2bf(v[j]);
    ((u16x4*)xb)[i] = o;
  }
}

// ---------------- K0b: W -> W^T bf16 (wt[n][k] = W[k][n]) ----------------
__global__ __launch_bounds__(256) void conv_wt(const float* __restrict__ w, unsigned short* __restrict__ wt)
{
  __shared__ float tl[64][65];
  const int k0 = blockIdx.x * 64;
  const int n0 = blockIdx.y * 64;
  const int c  = threadIdx.x & 63;
  const int r4 = threadIdx.x >> 6;
  #pragma unroll
  for (int i = 0; i < 16; i++){
    const int r = r4 * 16 + i;
    tl[r][c] = w[(size_t)(k0 + r) * DOUT + n0 + c];
  }
  __syncthreads();
  #pragma unroll
  for (int i = 0; i < 16; i++){
    const int n = r4 * 16 + i;
    wt[(size_t)(n0 + n) * DIN + k0 + c] = f2bf(tl[c][n]);
  }
}

// ---------------- K1: gate GEMM, f32 (accuracy-critical for top-k) ----------
// tile: 64 rows x 256 cols, K split in 2 (grid.y) for occupancy; 8x8 micro-tile.
__global__ __launch_bounds__(256) void gate_gemm(
    const float* __restrict__ x, const float* __restrict__ gw,
    float* __restrict__ part)
{
  __shared__ float xT[64][68];    // [k][row], padded
  __shared__ float wT[64][260];   // [k][col], padded
  const int b0 = blockIdx.x * 64;
  const int ks = blockIdx.y;      // K-split 0/1
  const int t  = threadIdx.x;
  const int ct = t & 31;          // col group: cols ct*4 and ct*4+128
  const int rt = t >> 5;          // row group: rows rt*8 .. rt*8+7

  float acc[8][2][4];
  #pragma unroll
  for (int i = 0; i < 8; i++)
    #pragma unroll
    for (int h = 0; h < 2; h++)
      #pragma unroll
      for (int j = 0; j < 4; j++) acc[i][h][j] = 0.f;

  const int koff = ks * 1024;
  for (int kc = 0; kc < 1024; kc += 64){
    { // stage x chunk transposed: 64 rows x 64 k
      const int row = t & 63, kb = (t >> 6) * 16;
      const float* src = &x[(size_t)(b0 + row) * DIN + koff + kc + kb];
      #pragma unroll
      for (int q4 = 0; q4 < 4; q4++){
        f32x4 a = *(const f32x4*)(src + q4 * 4);
        #pragma unroll
        for (int j = 0; j < 4; j++) xT[kb + q4 * 4 + j][row] = a[j];
      }
    }
    { // stage gw chunk: 64 k x 256 cols
      const int c4 = (t & 63) * 4, kq = t >> 6;
      #pragma unroll
      for (int i = 0; i < 16; i++){
        const int k = kq * 16 + i;
        *(f32x4*)&wT[k][c4] = *(const f32x4*)&gw[(size_t)(koff + kc + k) * NB + c4];
      }
    }
    __syncthreads();
    #pragma unroll 8
    for (int k = 0; k < 64; k++){
      f32x4 xv0 = *(const f32x4*)&xT[k][rt * 8];
      f32x4 xv1 = *(const f32x4*)&xT[k][rt * 8 + 4];
      f32x4 wv0 = *(const f32x4*)&wT[k][ct * 4];
      f32x4 wv1 = *(const f32x4*)&wT[k][ct * 4 + 128];
      #pragma unroll
      for (int j = 0; j < 4; j++){
        #pragma unroll
        for (int i = 0; i < 4; i++){
          acc[i][0][j]     = fmaf(xv0[i], wv0[j], acc[i][0][j]);
          acc[i + 4][0][j] = fmaf(xv1[i], wv0[j], acc[i + 4][0][j]);
          acc[i][1][j]     = fmaf(xv0[i], wv1[j], acc[i][1][j]);
          acc[i + 4][1][j] = fmaf(xv1[i], wv1[j], acc[i + 4][1][j]);
        }
      }
    }
    __syncthreads();
  }
  float* dst = part + (size_t)ks * BATCH * NB;
  #pragma unroll
  for (int i = 0; i < 8; i++){
    const int row = b0 + rt * 8 + i;
    #pragma unroll
    for (int h = 0; h < 2; h++){
      f32x4 o;
      #pragma unroll
      for (int j = 0; j < 4; j++) o[j] = acc[i][h][j];
      *(f32x4*)&dst[(size_t)row * NB + ct * 4 + h * 128] = o;
    }
  }
}

// ---------------- K2: reduce partials + bias, top-26 threshold, renormalize --
// one wave per row; exact k-th-largest via 26 max-extractions (tie-exact).
__global__ __launch_bounds__(256) void topk(float* __restrict__ part, const float* __restrict__ gb)
{
  const int lane = threadIdx.x & 63;
  const int row  = blockIdx.x * 4 + (threadIdx.x >> 6);
  f32x4* p0 = (f32x4*)&part[(size_t)row * NB];
  const f32x4* p1 = (const f32x4*)&part[(size_t)(BATCH + row) * NB];
  const f32x4* gbv = (const f32x4*)gb;
  f32x4 v = p0[lane] + p1[lane] + gbv[lane];

  const float NEG = -3.402823466e38f;
  float w0 = v[0], w1 = v[1], w2 = v[2], w3 = v[3];
  float thr = 0.f;
  for (int it = 0; it < KSEL; it++){
    float lm = fmaxf(fmaxf(w0, w1), fmaxf(w2, w3));
    float wm = lm;
    #pragma unroll
    for (int off = 32; off; off >>= 1) wm = fmaxf(wm, __shfl_xor(wm, off, 64));
    unsigned long long ball = __ballot(lm == wm);
    int first = __ffsll(ball) - 1;
    if (lane == first){
      if      (w0 == wm) w0 = NEG;
      else if (w1 == wm) w1 = NEG;
      else if (w2 == wm) w2 = NEG;
      else               w3 = NEG;
    }
    thr = wm;
  }
  float s = 0.f;
  #pragma unroll
  for (int j = 0; j < 4; j++) s += (v[j] >= thr) ? v[j] : 0.f;
  #pragma unroll
  for (int off = 32; off; off >>= 1) s += __shfl_xor(s, off, 64);
  const float d = s * (1.0f / NB);   // matches ref: res / (sum/n)
  f32x4 o;
  #pragma unroll
  for (int j = 0; j < 4; j++) o[j] = (v[j] >= thr) ? v[j] / d : 0.f;
  p0[lane] = o;                      // final gates overwrite partial 0
}

// ---------------- K3: gated main GEMM, bf16 MFMA 16x16x32 -------------------
// block: 128 rows x 128 cols (one output block q). 4 waves, each 64x64.
// gate folded into A during LDS staging. BK=64 (LDS < 64KB).
__global__ __launch_bounds__(256) void main_gemm(
    const unsigned short* __restrict__ xb,
    const unsigned short* __restrict__ wt,
    const float* __restrict__ g,
    const float* __restrict__ bias,
    float* __restrict__ out)
{
  __shared__ unsigned short xa[128][72];   // [row][k] gated bf16, +8 pad
  __shared__ unsigned short wb[128][72];   // [n][k]   bf16 (W^T), +8 pad
  __shared__ float gl[128 * 17];           // gates [row][p], stride 17

  const int q    = blockIdx.x;             // output block col 0..15
  const int b0   = blockIdx.y * 128;       // batch row tile
  const int t    = threadIdx.x;
  const int lane = t & 63;
  const int wid  = t >> 6;
  const int wr   = (wid >> 1) * 64;
  const int wc   = (wid & 1) * 64;
  const int l15  = lane & 15;
  const int l4   = lane >> 4;

  for (int e = t; e < 128 * 16; e += 256){
    const int r = e >> 4, p = e & 15;
    gl[r * 17 + p] = g[(size_t)(b0 + r) * NB + p * 16 + q];
  }

  f32x4 acc[4][4];
  #pragma unroll
  for (int m = 0; m < 4; m++)
    #pragma unroll
    for (int n = 0; n < 4; n++) acc[m][n] = (f32x4)0.0f;

  const int row_s = t >> 1;
  const int half  = t & 1;

  for (int kp = 0; kp < 32; kp++){         // 32 K-slices of 64 (p = kp>>1)
    const int p = kp >> 1;
    __syncthreads();                        // protect LDS reuse (covers gl on kp=0)
    { // stage gated A: x * gate -> bf16
      const float gate = gl[row_s * 17 + p];
      const unsigned short* src = &xb[(size_t)(b0 + row_s) * DIN + kp * 64 + half * 32];
      unsigned short* dst = &xa[row_s][half * 32];
      #pragma unroll
      for (int c = 0; c < 4; c++){
        u16x8 u = *(const u16x8*)(src + c * 8);
        u16x8 o;
        #pragma unroll
        for (int j = 0; j < 8; j++) o[j] = f2bf(bf2f(u[j]) * gate);
        *(u16x8*)(dst + c * 8) = o;
      }
    }
    { // stage B: W^T tile copy
      const unsigned short* src = &wt[(size_t)(q * 128 + row_s) * DIN + kp * 64 + half * 32];
      unsigned short* dst = &wb[row_s][half * 32];
      #pragma unroll
      for (int c = 0; c < 4; c++)
        *(u16x8*)(dst + c * 8) = *(const u16x8*)(src + c * 8);
    }
    __syncthreads();
    #pragma unroll
    for (int ksi = 0; ksi < 2; ksi++){
      const int kk = ksi * 32 + l4 * 8;
      bf16x8 a[4], b[4];
      #pragma unroll
      for (int m = 0; m < 4; m++)
        a[m] = *(const bf16x8*)&xa[wr + m * 16 + l15][kk];
      #pragma unroll
      for (int n = 0; n < 4; n++)
        b[n] = *(const bf16x8*)&wb[wc + n * 16 + l15][kk];
      #pragma unroll
      for (int m = 0; m < 4; m++)
        #pragma unroll
        for (int n = 0; n < 4; n++)
          acc[m][n] = __builtin_amdgcn_mfma_f32_16x16x32_bf16(a[m], b[n], acc[m][n], 0, 0, 0);
    }
  }

  #pragma unroll
  for (int n = 0; n < 4; n++){
    const int col = q * 128 + wc + n * 16 + l15;
    const float bv = bias[col];
    #pragma unroll
    for (int m = 0; m < 4; m++){
      #pragma unroll
      for (int r = 0; r < 4; r++){
        const int row = b0 + wr + m * 16 + l4 * 4 + r;   // C/D: row=(lane>>4)*4+reg
        out[(size_t)row * DOUT + col] = acc[m][n][r] + bv;
      }
    }
  }
}

// ---------------- launch -----------------------------------------------------
extern "C" void kernel_launch(void* const* d_in, const int* in_sizes, int n_in,
                              void* d_out, int out_size, void* d_ws, size_t ws_size,
                              hipStream_t stream)
{
  const float* x    = (const float*)d_in[0];
  const float* w    = (const float*)d_in[1];
  const float* bias = (const float*)d_in[2];
  const float* gw   = (const float*)d_in[3];
  const float* gb   = (const float*)d_in[4];
  float* out = (float*)d_out;

  // ws layout: [0,16MB) gate partials (partial0 becomes final gates),
  //            [16MB,48MB) x bf16, [48MB,56MB) W^T bf16
  float*          part = (float*)d_ws;
  unsigned short* xb   = (unsigned short*)((char*)d_ws + (size_t)16 * 1024 * 1024);
  unsigned short* wtb  = (unsigned short*)((char*)d_ws + (size_t)48 * 1024 * 1024);

  conv_x   <<<2048, 256, 0, stream>>>(x, xb, BATCH * DIN / 4);
  conv_wt  <<<dim3(DIN / 64, DOUT / 64), 256, 0, stream>>>(w, wtb);
  gate_gemm<<<dim3(BATCH / 64, 2), 256, 0, stream>>>(x, gw, part);
  topk     <<<BATCH / 4, 256, 0, stream>>>(part, gb);
  main_gemm<<<dim3(16, BATCH / 128), 256, 0, stream>>>(xb, wtb, part, bias, out);
}

// Round 2
// 269.187 us; speedup vs baseline: 1.0923x; 1.0923x over previous
//
#include <hip/hip_runtime.h>
#include <hip/hip_bf16.h>
#include <stdint.h>

#define BATCH  8192
#define DIN    2048
#define DOUT   2048
#define NB     256
#define KSEL   26   // ceil(0.1*256)

typedef __attribute__((ext_vector_type(4))) float f32x4;
typedef __attribute__((ext_vector_type(8))) __bf16 bf16x8;
typedef __attribute__((ext_vector_type(8))) unsigned short u16x8;
typedef __attribute__((ext_vector_type(4))) unsigned short u16x4;

__device__ __forceinline__ float bf2f(unsigned short u){
  union { unsigned int i; float f; } v; v.i = ((unsigned int)u) << 16; return v.f;
}
__device__ __forceinline__ unsigned short f2bf(float f){
  union { float f; unsigned int i; } v; v.f = f;
  unsigned int x = v.i;
  return (unsigned short)((x + 0x7FFFu + ((x >> 16) & 1u)) >> 16);  // RNE
}
// native cast path — compiler emits v_cvt_pk_bf16_f32 for pairs (RNE)
__device__ __forceinline__ unsigned short f2bf_c(float f){
  __bf16 b = (__bf16)f;
  union { __bf16 b; unsigned short u; } v; v.b = b; return v.u;
}

// ---------------- K0b: W -> W^T bf16 (wt[n][k] = W[k][n]) ----------------
__global__ __launch_bounds__(256) void conv_wt(const float* __restrict__ w, unsigned short* __restrict__ wt)
{
  __shared__ float tl[64][65];
  const int k0 = blockIdx.x * 64;
  const int n0 = blockIdx.y * 64;
  const int c  = threadIdx.x & 63;
  const int r4 = threadIdx.x >> 6;
  #pragma unroll
  for (int i = 0; i < 16; i++){
    const int r = r4 * 16 + i;
    tl[r][c] = w[(size_t)(k0 + r) * DOUT + n0 + c];
  }
  __syncthreads();
  #pragma unroll
  for (int i = 0; i < 16; i++){
    const int n = r4 * 16 + i;
    wt[(size_t)(n0 + n) * DIN + k0 + c] = f2bf(tl[c][n]);
  }
}

// ---------------- K1: gate GEMM, f32 (accuracy-critical for top-k) ----------
// tile: 32 rows x 256 cols, BK=32, K-split 2 -> 512 blocks (2/CU, 8 waves/CU).
// Also emits bf16 copy of x (each x element touched exactly once grid-wide).
__global__ __launch_bounds__(256) void gate_gemm(
    const float* __restrict__ x, const float* __restrict__ gw,
    float* __restrict__ part, unsigned short* __restrict__ xb)
{
  __shared__ float xT[32][36];    // [k][row], padded
  __shared__ float wT[32][260];   // [k][col], padded
  const int b0 = blockIdx.x * 32;
  const int ks = blockIdx.y;      // K-split 0/1
  const int t  = threadIdx.x;
  const int ct = t & 31;          // cols ct*4 and ct*4+128
  const int rt = t >> 5;          // rows rt*4 .. rt*4+3

  f32x4 acc0[4], acc1[4];
  #pragma unroll
  for (int i = 0; i < 4; i++){ acc0[i] = (f32x4)0.0f; acc1[i] = (f32x4)0.0f; }

  // staging maps
  const int sr  = t >> 3;         // x-stage row 0..31
  const int sk  = (t & 7) * 4;    // x-stage k offset (f32x4)
  const int wk  = (t >> 6) * 8;   // gw-stage k base (8 rows per wave)
  const int wc4 = (t & 63) * 4;   // gw-stage col (f32x4)

  const int koff = ks * 1024;
  for (int kc = 0; kc < 1024; kc += 32){
    { // stage x transposed + emit bf16 x
      const size_t gi = (size_t)(b0 + sr) * DIN + koff + kc + sk;
      f32x4 a = *(const f32x4*)&x[gi];
      u16x4 ob;
      #pragma unroll
      for (int j = 0; j < 4; j++) ob[j] = f2bf_c(a[j]);
      *(u16x4*)&xb[gi] = ob;
      #pragma unroll
      for (int j = 0; j < 4; j++) xT[sk + j][sr] = a[j];
    }
    { // stage gw chunk: 32 k x 256 cols
      #pragma unroll
      for (int i = 0; i < 8; i++){
        const int k = wk + i;
        *(f32x4*)&wT[k][wc4] = *(const f32x4*)&gw[(size_t)(koff + kc + k) * NB + wc4];
      }
    }
    __syncthreads();
    #pragma unroll 8
    for (int k = 0; k < 32; k++){
      f32x4 xv  = *(const f32x4*)&xT[k][rt * 4];
      f32x4 wv0 = *(const f32x4*)&wT[k][ct * 4];
      f32x4 wv1 = *(const f32x4*)&wT[k][ct * 4 + 128];
      #pragma unroll
      for (int i = 0; i < 4; i++){
        acc0[i] += xv[i] * wv0;
        acc1[i] += xv[i] * wv1;
      }
    }
    __syncthreads();
  }
  float* dst = part + (size_t)ks * BATCH * NB;
  #pragma unroll
  for (int i = 0; i < 4; i++){
    const int row = b0 + rt * 4 + i;
    *(f32x4*)&dst[(size_t)row * NB + ct * 4]       = acc0[i];
    *(f32x4*)&dst[(size_t)row * NB + ct * 4 + 128] = acc1[i];
  }
}

// ---------------- K2: reduce partials + bias, top-26 threshold, renormalize --
__global__ __launch_bounds__(256) void topk(float* __restrict__ part, const float* __restrict__ gb)
{
  const int lane = threadIdx.x & 63;
  const int row  = blockIdx.x * 4 + (threadIdx.x >> 6);
  f32x4* p0 = (f32x4*)&part[(size_t)row * NB];
  const f32x4* p1 = (const f32x4*)&part[(size_t)(BATCH + row) * NB];
  const f32x4* gbv = (const f32x4*)gb;
  f32x4 v = p0[lane] + p1[lane] + gbv[lane];

  const float NEG = -3.402823466e38f;
  float w0 = v[0], w1 = v[1], w2 = v[2], w3 = v[3];
  float thr = 0.f;
  for (int it = 0; it < KSEL; it++){
    float lm = fmaxf(fmaxf(w0, w1), fmaxf(w2, w3));
    float wm = lm;
    #pragma unroll
    for (int off = 32; off; off >>= 1) wm = fmaxf(wm, __shfl_xor(wm, off, 64));
    unsigned long long ball = __ballot(lm == wm);
    int first = __ffsll(ball) - 1;
    if (lane == first){
      if      (w0 == wm) w0 = NEG;
      else if (w1 == wm) w1 = NEG;
      else if (w2 == wm) w2 = NEG;
      else               w3 = NEG;
    }
    thr = wm;
  }
  float s = 0.f;
  #pragma unroll
  for (int j = 0; j < 4; j++) s += (v[j] >= thr) ? v[j] : 0.f;
  #pragma unroll
  for (int off = 32; off; off >>= 1) s += __shfl_xor(s, off, 64);
  const float d = s * (1.0f / NB);   // matches ref: res / (sum/n)
  f32x4 o;
  #pragma unroll
  for (int j = 0; j < 4; j++) o[j] = (v[j] >= thr) ? v[j] / d : 0.f;
  p0[lane] = o;                      // final gates overwrite partial 0
}

// ---------------- K3: gated main GEMM, bf16 MFMA 16x16x32 -------------------
// block: 128 rows x 128 cols (one output block q). 4 waves, each 64x64.
// gate folded into A during LDS staging (native bf16 casts -> cvt_pk). BK=64.
__global__ __launch_bounds__(256) void main_gemm(
    const unsigned short* __restrict__ xb,
    const unsigned short* __restrict__ wt,
    const float* __restrict__ g,
    const float* __restrict__ bias,
    float* __restrict__ out)
{
  __shared__ unsigned short xa[128][72];   // [row][k] gated bf16, +8 pad
  __shared__ unsigned short wb[128][72];   // [n][k]   bf16 (W^T), +8 pad
  __shared__ float gl[128 * 17];           // gates [row][p], stride 17

  const int q    = blockIdx.x;             // output block col 0..15
  const int b0   = blockIdx.y * 128;       // batch row tile
  const int t    = threadIdx.x;
  const int lane = t & 63;
  const int wid  = t >> 6;
  const int wr   = (wid >> 1) * 64;
  const int wc   = (wid & 1) * 64;
  const int l15  = lane & 15;
  const int l4   = lane >> 4;

  for (int e = t; e < 128 * 16; e += 256){
    const int r = e >> 4, p = e & 15;
    gl[r * 17 + p] = g[(size_t)(b0 + r) * NB + p * 16 + q];
  }

  f32x4 acc[4][4];
  #pragma unroll
  for (int m = 0; m < 4; m++)
    #pragma unroll
    for (int n = 0; n < 4; n++) acc[m][n] = (f32x4)0.0f;

  const int row_s = t >> 1;
  const int half  = t & 1;

  for (int kp = 0; kp < 32; kp++){         // 32 K-slices of 64 (p = kp>>1)
    const int p = kp >> 1;
    __syncthreads();                        // protect LDS reuse (covers gl on kp=0)
    { // stage gated A: xb * gate -> bf16 (cheap path: lshl + mul + cvt_pk)
      const float gate = gl[row_s * 17 + p];
      const unsigned short* src = &xb[(size_t)(b0 + row_s) * DIN + kp * 64 + half * 32];
      unsigned short* dst = &xa[row_s][half * 32];
      #pragma unroll
      for (int c = 0; c < 4; c++){
        u16x8 u = *(const u16x8*)(src + c * 8);
        u16x8 o;
        #pragma unroll
        for (int j = 0; j < 8; j++) o[j] = f2bf_c(bf2f(u[j]) * gate);
        *(u16x8*)(dst + c * 8) = o;
      }
    }
    { // stage B: W^T tile copy
      const unsigned short* src = &wt[(size_t)(q * 128 + row_s) * DIN + kp * 64 + half * 32];
      unsigned short* dst = &wb[row_s][half * 32];
      #pragma unroll
      for (int c = 0; c < 4; c++)
        *(u16x8*)(dst + c * 8) = *(const u16x8*)(src + c * 8);
    }
    __syncthreads();
    #pragma unroll
    for (int ksi = 0; ksi < 2; ksi++){
      const int kk = ksi * 32 + l4 * 8;
      bf16x8 a[4], b[4];
      #pragma unroll
      for (int m = 0; m < 4; m++)
        a[m] = *(const bf16x8*)&xa[wr + m * 16 + l15][kk];
      #pragma unroll
      for (int n = 0; n < 4; n++)
        b[n] = *(const bf16x8*)&wb[wc + n * 16 + l15][kk];
      #pragma unroll
      for (int m = 0; m < 4; m++)
        #pragma unroll
        for (int n = 0; n < 4; n++)
          acc[m][n] = __builtin_amdgcn_mfma_f32_16x16x32_bf16(a[m], b[n], acc[m][n], 0, 0, 0);
    }
  }

  #pragma unroll
  for (int n = 0; n < 4; n++){
    const int col = q * 128 + wc + n * 16 + l15;
    const float bv = bias[col];
    #pragma unroll
    for (int m = 0; m < 4; m++){
      #pragma unroll
      for (int r = 0; r < 4; r++){
        const int row = b0 + wr + m * 16 + l4 * 4 + r;   // C/D: row=(lane>>4)*4+reg
        out[(size_t)row * DOUT + col] = acc[m][n][r] + bv;
      }
    }
  }
}

// ---------------- launch -----------------------------------------------------
extern "C" void kernel_launch(void* const* d_in, const int* in_sizes, int n_in,
                              void* d_out, int out_size, void* d_ws, size_t ws_size,
                              hipStream_t stream)
{
  const float* x    = (const float*)d_in[0];
  const float* w    = (const float*)d_in[1];
  const float* bias = (const float*)d_in[2];
  const float* gw   = (const float*)d_in[3];
  const float* gb   = (const float*)d_in[4];
  float* out = (float*)d_out;

  // ws layout: [0,16MB) gate partials (partial 0 becomes final gates),
  //            [16MB,24MB) W^T bf16, [24MB,56MB) x bf16
  float*          part = (float*)d_ws;
  unsigned short* wtb  = (unsigned short*)((char*)d_ws + (size_t)16 * 1024 * 1024);
  unsigned short* xbb  = (unsigned short*)((char*)d_ws + (size_t)24 * 1024 * 1024);

  conv_wt  <<<dim3(DIN / 64, DOUT / 64), 256, 0, stream>>>(w, wtb);
  gate_gemm<<<dim3(BATCH / 32, 2), 256, 0, stream>>>(x, gw, part, xbb);
  topk     <<<BATCH / 4, 256, 0, stream>>>(part, gb);
  main_gemm<<<dim3(16, BATCH / 128), 256, 0, stream>>>(xbb, wtb, part, bias, out);
}